// Round 1
// baseline (1675.296 us; speedup 1.0000x reference)
//
#include <hip/hip_runtime.h>
#include <hip/hip_bf16.h>
#include <math.h>

// ---------------- problem constants ----------------
#define BB 32
#define NN 512
#define BN 16384          // BB*NN
#define DD 1024
#define HID 512
#define G4 2048           // 4*HID
#define HLEN 15
#define IND 4
#define EPS 1e-5f

typedef __bf16 v8bf __attribute__((ext_vector_type(8)));
typedef float  v4f  __attribute__((ext_vector_type(4)));

// ---------------- weight conversion fp32 -> bf16 ----------------
__global__ void convert_w(const float* __restrict__ Whh, const float* __restrict__ Wrel,
                          __bf16* __restrict__ whh_b, __bf16* __restrict__ wrel_b) {
    int i = blockIdx.x * 256 + threadIdx.x;
    if (i < G4 * HID)  whh_b[i]  = (__bf16)Whh[i];
    if (i < DD * HID)  wrel_b[i] = (__bf16)Wrel[i];
}

// ---------------- zero h (bf16) and c (fp32) ----------------
__global__ void init_hc(__bf16* __restrict__ h, float* __restrict__ c) {
    int i = blockIdx.x * 256 + threadIdx.x;   // < BN*HID
    h[i] = (__bf16)0.0f;
    c[i] = 0.0f;
}

// ---------------- per-batch gate alpha ----------------
__global__ void alpha_kernel(const float* __restrict__ es, const float* __restrict__ gc,
                             const float* __restrict__ W_g1, const float* __restrict__ b_g1,
                             const float* __restrict__ W_g2, const float* __restrict__ b_g2,
                             float* __restrict__ alpha) {
    int b = threadIdx.x;
    if (b >= BB) return;
    float c0 = es[b], c1 = gc[b];
    float acc = b_g2[0];
    for (int k = 0; k < 16; ++k) {
        float hk = c0 * W_g1[k * 2] + c1 * W_g1[k * 2 + 1] + b_g1[k];
        hk = fmaxf(hk, 0.0f);
        acc += hk * W_g2[k];
    }
    alpha[b] = 1.0f / (1.0f + expf(-acc));
}

// ---------------- bf16 MFMA GEMM: C(MxN) = A(MxK) * B(NxK)^T ----------------
// 128x128 block tile, BK=32, 256 threads = 4 waves in 2x2, each wave 64x64 (4x4 MFMA tiles)
template<bool STORE_F32>
__global__ __launch_bounds__(256) void gemm_bt(const __bf16* __restrict__ A,
                                               const __bf16* __restrict__ Bm,
                                               void* __restrict__ Cout,
                                               int M, int Nn, int K) {
    __shared__ __bf16 sA[128][32];
    __shared__ __bf16 sB[128][32];
    const int tid  = threadIdx.x;
    const int lane = tid & 63;
    const int wave = tid >> 6;
    const int wm = (wave & 1) * 64;
    const int wn = (wave >> 1) * 64;
    const int bm = blockIdx.x;
    const int bn = blockIdx.y;

    v4f acc[4][4] = {};

    const int arow  = tid >> 2;        // 0..63
    const int akseg = (tid & 3) * 8;   // 0,8,16,24

    const __bf16* Ab = A  + (size_t)bm * 128 * K;
    const __bf16* Bb = Bm + (size_t)bn * 128 * K;

    const int kq   = (lane >> 4) * 8;  // k offset within BK for fragments
    const int mrow = lane & 15;

    for (int k0 = 0; k0 < K; k0 += 32) {
        *(uint4*)&sA[arow][akseg]      = *(const uint4*)&Ab[(size_t)arow * K + k0 + akseg];
        *(uint4*)&sA[arow + 64][akseg] = *(const uint4*)&Ab[(size_t)(arow + 64) * K + k0 + akseg];
        *(uint4*)&sB[arow][akseg]      = *(const uint4*)&Bb[(size_t)arow * K + k0 + akseg];
        *(uint4*)&sB[arow + 64][akseg] = *(const uint4*)&Bb[(size_t)(arow + 64) * K + k0 + akseg];
        __syncthreads();

        v8bf af[4], bfr[4];
        #pragma unroll
        for (int i = 0; i < 4; ++i) af[i]  = *(v8bf*)&sA[wm + i * 16 + mrow][kq];
        #pragma unroll
        for (int j = 0; j < 4; ++j) bfr[j] = *(v8bf*)&sB[wn + j * 16 + mrow][kq];
        #pragma unroll
        for (int i = 0; i < 4; ++i)
            #pragma unroll
            for (int j = 0; j < 4; ++j)
                acc[i][j] = __builtin_amdgcn_mfma_f32_16x16x32_bf16(af[i], bfr[j], acc[i][j], 0, 0, 0);
        __syncthreads();
    }

    // C/D layout: col = lane&15, row = (lane>>4)*4 + reg
    const int ccol  = lane & 15;
    const int crow4 = (lane >> 4) * 4;
    #pragma unroll
    for (int i = 0; i < 4; ++i) {
        #pragma unroll
        for (int j = 0; j < 4; ++j) {
            int gm = bm * 128 + wm + i * 16 + crow4;
            int gn = bn * 128 + wn + j * 16 + ccol;
            #pragma unroll
            for (int r = 0; r < 4; ++r) {
                float v = acc[i][j][r];
                if (STORE_F32) ((float*)Cout)[(size_t)(gm + r) * Nn + gn] = v;
                else           ((__bf16*)Cout)[(size_t)(gm + r) * Nn + gn] = (__bf16)v;
            }
        }
    }
}

// ---------------- LSTM cell pointwise update ----------------
// gates: BN x 2048 bf16 (= h_prev @ W_hh^T). Adds bias + x_t@W_ih^T, applies nonlinearity.
__global__ __launch_bounds__(256) void lstm_cell(const __bf16* __restrict__ gates,
                                                 const float* __restrict__ traj,
                                                 const float* __restrict__ W_ih,
                                                 const float* __restrict__ b_ih,
                                                 const float* __restrict__ b_hh,
                                                 float* __restrict__ c,
                                                 __bf16* __restrict__ h,
                                                 int t) {
    int idx = blockIdx.x * 256 + threadIdx.x;   // bn*512 + u
    int bn = idx >> 9;
    int u  = idx & 511;
    const float* x = traj + (size_t)bn * (HLEN * IND) + t * IND;
    float x0 = x[0], x1 = x[1], x2 = x[2], x3 = x[3];

    float g[4];
    #pragma unroll
    for (int gi = 0; gi < 4; ++gi) {
        int j = gi * HID + u;
        const float* w = W_ih + (size_t)j * IND;
        g[gi] = (float)gates[(size_t)bn * G4 + j] + b_ih[j] + b_hh[j]
              + x0 * w[0] + x1 * w[1] + x2 * w[2] + x3 * w[3];
    }
    float ig = 1.0f / (1.0f + expf(-g[0]));
    float fg = 1.0f / (1.0f + expf(-g[1]));
    float gg = tanhf(g[2]);
    float og = 1.0f / (1.0f + expf(-g[3]));
    float cn = fg * c[idx] + ig * gg;
    c[idx] = cn;
    h[idx] = (__bf16)(og * tanhf(cn));
}

// ---------------- fused gate-mix + residual + LayerNorm ----------------
__global__ __launch_bounds__(256) void fuse_ln(const float* __restrict__ tokens,
                                               const float* __restrict__ hrel,
                                               const float* __restrict__ habs_in,
                                               const float* __restrict__ W_abs,
                                               const float* __restrict__ alpha,
                                               const float* __restrict__ gamma,
                                               const float* __restrict__ beta,
                                               float* __restrict__ out) {
    const int row = blockIdx.x;        // 0..BN-1
    const int b   = row >> 9;          // row / NN
    const float al = alpha[b];
    const float a0 = habs_in[(size_t)row * 2];
    const float a1 = habs_in[(size_t)row * 2 + 1];
    const int tid  = threadIdx.x;
    const int lane = tid & 63;
    const int wave = tid >> 6;

    __shared__ float red[4];

    float x[4];
    float s = 0.0f;
    #pragma unroll
    for (int q = 0; q < 4; ++q) {
        int dcol = tid + q * 256;
        float habs = a0 * W_abs[dcol * 2] + a1 * W_abs[dcol * 2 + 1];
        float v = tokens[(size_t)row * DD + dcol]
                + al * hrel[(size_t)row * DD + dcol]
                + (1.0f - al) * habs;
        x[q] = v;
        s += v;
    }
    #pragma unroll
    for (int off = 32; off > 0; off >>= 1) s += __shfl_down(s, off);
    if (lane == 0) red[wave] = s;
    __syncthreads();
    float mu = (red[0] + red[1] + red[2] + red[3]) * (1.0f / DD);

    float vs = 0.0f;
    #pragma unroll
    for (int q = 0; q < 4; ++q) {
        float d = x[q] - mu;
        vs += d * d;
    }
    #pragma unroll
    for (int off = 32; off > 0; off >>= 1) vs += __shfl_down(vs, off);
    __syncthreads();                 // red[] reads above complete before overwrite
    if (lane == 0) red[wave] = vs;
    __syncthreads();
    float var = (red[0] + red[1] + red[2] + red[3]) * (1.0f / DD);
    float rstd = rsqrtf(var + EPS);

    #pragma unroll
    for (int q = 0; q < 4; ++q) {
        int dcol = tid + q * 256;
        out[(size_t)row * DD + dcol] = (x[q] - mu) * rstd * gamma[dcol] + beta[dcol];
    }
}

// ---------------- host launch ----------------
extern "C" void kernel_launch(void* const* d_in, const int* in_sizes, int n_in,
                              void* d_out, int out_size, void* d_ws, size_t ws_size,
                              hipStream_t stream) {
    const float* tokens   = (const float*)d_in[0];
    const float* traj     = (const float*)d_in[1];
    const float* habs     = (const float*)d_in[2];
    const float* espeed   = (const float*)d_in[3];
    const float* gconf    = (const float*)d_in[4];
    const float* W_ih     = (const float*)d_in[5];
    const float* W_hh     = (const float*)d_in[6];
    const float* b_ih     = (const float*)d_in[7];
    const float* b_hh     = (const float*)d_in[8];
    const float* W_rel    = (const float*)d_in[9];
    const float* W_abs    = (const float*)d_in[10];
    const float* W_g1     = (const float*)d_in[11];
    const float* b_g1     = (const float*)d_in[12];
    const float* W_g2     = (const float*)d_in[13];
    const float* b_g2     = (const float*)d_in[14];
    const float* gamma    = (const float*)d_in[15];
    const float* beta     = (const float*)d_in[16];
    float* out = (float*)d_out;

    char* ws = (char*)d_ws;
    size_t off = 0;
    __bf16* whh_b  = (__bf16*)(ws + off); off += (size_t)G4 * HID * 2;     // 2 MB
    __bf16* wrel_b = (__bf16*)(ws + off); off += (size_t)DD * HID * 2;     // 1 MB
    __bf16* h      = (__bf16*)(ws + off); off += (size_t)BN * HID * 2;     // 16 MB
    float*  c      = (float*)(ws + off);  off += (size_t)BN * HID * 4;     // 32 MB
    __bf16* gates  = (__bf16*)(ws + off); off += (size_t)BN * G4 * 2;      // 64 MB
    float*  hrel   = (float*)(ws + off);  off += (size_t)BN * DD * 4;      // 64 MB
    float*  alpha  = (float*)(ws + off);  off += 256;

    convert_w<<<(G4 * HID + 255) / 256, 256, 0, stream>>>(W_hh, W_rel, whh_b, wrel_b);
    init_hc<<<(BN * HID) / 256, 256, 0, stream>>>(h, c);
    alpha_kernel<<<1, 64, 0, stream>>>(espeed, gconf, W_g1, b_g1, W_g2, b_g2, alpha);

    for (int t = 0; t < HLEN; ++t) {
        gemm_bt<false><<<dim3(BN / 128, G4 / 128), 256, 0, stream>>>(h, whh_b, gates, BN, G4, HID);
        lstm_cell<<<(BN * HID) / 256, 256, 0, stream>>>(gates, traj, W_ih, b_ih, b_hh, c, h, t);
    }

    gemm_bt<true><<<dim3(BN / 128, DD / 128), 256, 0, stream>>>(h, wrel_b, hrel, BN, DD, HID);
    fuse_ln<<<BN, 256, 0, stream>>>(tokens, hrel, habs, W_abs, alpha, gamma, beta, out);
}

// Round 2
// 1377.711 us; speedup vs baseline: 1.2160x; 1.2160x over previous
//
#include <hip/hip_runtime.h>
#include <hip/hip_bf16.h>
#include <math.h>

// ---------------- problem constants ----------------
#define BB 32
#define NN 512
#define BN 16384          // BB*NN
#define DD 1024
#define HID 512
#define G4 2048           // 4*HID
#define HLEN 15
#define IND 4
#define EPS 1e-5f
#define CLD 132           // padded LDS C stride (bf16): 264B = 66 words ≡ 2 mod 32 -> conflict-free epilogue stores

typedef __bf16 v8bf __attribute__((ext_vector_type(8)));
typedef float  v4f  __attribute__((ext_vector_type(4)));

__device__ __forceinline__ void async_copy16(const __bf16* gsrc, __bf16* ldst) {
    __builtin_amdgcn_global_load_lds(
        (const __attribute__((address_space(1))) void*)gsrc,
        (__attribute__((address_space(3))) void*)ldst, 16, 0, 0);
}

__device__ __forceinline__ float sigmf(float x) { return 1.0f / (1.0f + expf(-x)); }

// ---------------- weight prep ----------------
// whh_b: gate-interleaved (j' = u*4+gi) bf16 2048x512; wrel_b: bf16 1024x512;
// wih_i: interleaved fp32 2048x4; bsum: b_ih+b_hh interleaved fp32 2048.
__global__ void convert_w(const float* __restrict__ Whh, const float* __restrict__ Wrel,
                          const float* __restrict__ Wih, const float* __restrict__ bih,
                          const float* __restrict__ bhh,
                          __bf16* __restrict__ whh_b, __bf16* __restrict__ wrel_b,
                          float* __restrict__ wih_i, float* __restrict__ bsum) {
    int i = blockIdx.x * 256 + threadIdx.x;
    if (i < G4 * HID) {
        int jp = i >> 9, k = i & 511;
        int uu = jp >> 2, gi = jp & 3;
        whh_b[i] = (__bf16)Whh[(size_t)(gi * HID + uu) * HID + k];
    }
    if (i < DD * HID) wrel_b[i] = (__bf16)Wrel[i];
    if (i < G4) {
        int uu = i >> 2, gi = i & 3;
        int src = gi * HID + uu;
        wih_i[i * 4 + 0] = Wih[src * 4 + 0];
        wih_i[i * 4 + 1] = Wih[src * 4 + 1];
        wih_i[i * 4 + 2] = Wih[src * 4 + 2];
        wih_i[i * 4 + 3] = Wih[src * 4 + 3];
        bsum[i] = bih[src] + bhh[src];
    }
}

// ---------------- per-batch gate alpha ----------------
__global__ void alpha_kernel(const float* __restrict__ es, const float* __restrict__ gc,
                             const float* __restrict__ W_g1, const float* __restrict__ b_g1,
                             const float* __restrict__ W_g2, const float* __restrict__ b_g2,
                             float* __restrict__ alpha) {
    int b = threadIdx.x;
    if (b >= BB) return;
    float c0 = es[b], c1 = gc[b];
    float acc = b_g2[0];
    for (int k = 0; k < 16; ++k) {
        float hk = c0 * W_g1[k * 2] + c1 * W_g1[k * 2 + 1] + b_g1[k];
        hk = fmaxf(hk, 0.0f);
        acc += hk * W_g2[k];
    }
    alpha[b] = sigmf(acc);
}

// ---------------- t=0 cell (h0 = c0 = 0 -> gates from input only) ----------------
__global__ __launch_bounds__(256) void lstm_cell0(const float* __restrict__ traj,
                                                  const float* __restrict__ wih_i,
                                                  const float* __restrict__ bsum,
                                                  float* __restrict__ c,
                                                  __bf16* __restrict__ h) {
    int idx = blockIdx.x * 256 + threadIdx.x;   // row*512 + u
    int row = idx >> 9;
    int u   = idx & 511;
    const float* x = traj + (size_t)row * (HLEN * IND);   // t = 0
    float x0 = x[0], x1 = x[1], x2 = x[2], x3 = x[3];
    float g[4];
    #pragma unroll
    for (int gi = 0; gi < 4; ++gi) {
        int j = u * 4 + gi;
        const float* w = wih_i + (size_t)j * 4;
        g[gi] = bsum[j] + w[0] * x0 + w[1] * x1 + w[2] * x2 + w[3] * x3;
    }
    float ig = sigmf(g[0]);
    float gg = tanhf(g[2]);
    float og = sigmf(g[3]);
    float cn = ig * gg;                    // f*c0 = 0
    c[idx] = cn;
    h[idx] = (__bf16)(og * tanhf(cn));
}

// ---------------- fused GEMM + LSTM cell ----------------
// C(16384 x 2048) = h_in(16384x512) @ whh^T (gate-interleaved), then cell update in epilogue.
// 128x128 tile, BK=32, 4 waves 2x2, global_load_lds staging.
__global__ __launch_bounds__(256) void gemm_lstm(const __bf16* __restrict__ A,
                                                 const __bf16* __restrict__ Bm,
                                                 const float* __restrict__ traj,
                                                 const float* __restrict__ wih_i,
                                                 const float* __restrict__ bsum,
                                                 float* __restrict__ c,
                                                 __bf16* __restrict__ h_out,
                                                 int t) {
    __shared__ union {
        struct { __bf16 a[128][32]; __bf16 b[128][32]; } s;
        __bf16 cst[128][CLD];
    } u;
    const int K = HID;
    const int tid  = threadIdx.x;
    const int lane = tid & 63;
    const int wave = tid >> 6;
    const int wm = (wave & 1) * 64;
    const int wn = (wave >> 1) * 64;
    const int bm = blockIdx.x;
    const int bn = blockIdx.y;

    v4f acc[4][4] = {};

    const int arow  = tid >> 2;        // 0..63
    const int akseg = (tid & 3) * 8;   // 0,8,16,24

    const __bf16* gA = A  + (size_t)bm * 128 * K + (size_t)arow * K + akseg;
    const __bf16* gB = Bm + (size_t)bn * 128 * K + (size_t)arow * K + akseg;
    __bf16* lA = &u.s.a[0][0] + wave * 512;     // lane writes at +lane*16B automatically
    __bf16* lB = &u.s.b[0][0] + wave * 512;

    const int kq   = (lane >> 4) * 8;
    const int mrow = lane & 15;

    for (int k0 = 0; k0 < K; k0 += 32) {
        async_copy16(gA,            lA);
        async_copy16(gA + 64 * K,   lA + 2048);
        async_copy16(gB,            lB);
        async_copy16(gB + 64 * K,   lB + 2048);
        gA += 32; gB += 32;
        __syncthreads();

        v8bf af[4], bfr[4];
        #pragma unroll
        for (int i = 0; i < 4; ++i) af[i]  = *(v8bf*)&u.s.a[wm + i * 16 + mrow][kq];
        #pragma unroll
        for (int j = 0; j < 4; ++j) bfr[j] = *(v8bf*)&u.s.b[wn + j * 16 + mrow][kq];
        #pragma unroll
        for (int i = 0; i < 4; ++i)
            #pragma unroll
            for (int j = 0; j < 4; ++j)
                acc[i][j] = __builtin_amdgcn_mfma_f32_16x16x32_bf16(af[i], bfr[j], acc[i][j], 0, 0, 0);
        __syncthreads();
    }

    // acc -> LDS (bf16, padded) ; C/D layout: col=lane&15, row=(lane>>4)*4+reg
    const int ccol  = lane & 15;
    const int crow4 = (lane >> 4) * 4;
    #pragma unroll
    for (int i = 0; i < 4; ++i)
        #pragma unroll
        for (int j = 0; j < 4; ++j)
            #pragma unroll
            for (int r = 0; r < 4; ++r)
                u.cst[wm + i * 16 + crow4 + r][wn + j * 16 + ccol] = (__bf16)acc[i][j][r];
    __syncthreads();

    // cell update: this block owns rows [bm*128,+128) x units [bn*32,+32)
    const int u_loc  = tid & 31;
    const int rgrp   = tid >> 5;
    const int u_glob = bn * 32 + u_loc;
    float wv[4][4], bs4[4];
    #pragma unroll
    for (int gi = 0; gi < 4; ++gi) {
        const float* wp = wih_i + (size_t)(u_glob * 4 + gi) * 4;
        wv[gi][0] = wp[0]; wv[gi][1] = wp[1]; wv[gi][2] = wp[2]; wv[gi][3] = wp[3];
        bs4[gi] = bsum[u_glob * 4 + gi];
    }
    for (int rr = rgrp; rr < 128; rr += 8) {
        int grow = bm * 128 + rr;
        const float* x = traj + (size_t)grow * (HLEN * IND) + t * IND;
        float x0 = x[0], x1 = x[1], x2 = x[2], x3 = x[3];
        float g[4];
        #pragma unroll
        for (int gi = 0; gi < 4; ++gi)
            g[gi] = (float)u.cst[rr][u_loc * 4 + gi] + bs4[gi]
                  + wv[gi][0] * x0 + wv[gi][1] * x1 + wv[gi][2] * x2 + wv[gi][3] * x3;
        float ig = sigmf(g[0]);
        float fg = sigmf(g[1]);
        float gg = tanhf(g[2]);
        float og = sigmf(g[3]);
        size_t ci = (size_t)grow * HID + u_glob;
        float cn = fg * c[ci] + ig * gg;
        c[ci] = cn;
        h_out[ci] = (__bf16)(og * tanhf(cn));
    }
}

// ---------------- projection GEMM: hrel(16384x1024) = h(16384x512) @ W_rel^T ----------------
__global__ __launch_bounds__(256) void gemm_proj(const __bf16* __restrict__ A,
                                                 const __bf16* __restrict__ Bm,
                                                 float* __restrict__ Cout) {
    __shared__ __bf16 sA[128][32];
    __shared__ __bf16 sB[128][32];
    const int K = HID, Nn = DD;
    const int tid  = threadIdx.x;
    const int lane = tid & 63;
    const int wave = tid >> 6;
    const int wm = (wave & 1) * 64;
    const int wn = (wave >> 1) * 64;
    const int bm = blockIdx.x;
    const int bn = blockIdx.y;

    v4f acc[4][4] = {};
    const int arow  = tid >> 2;
    const int akseg = (tid & 3) * 8;

    const __bf16* gA = A  + (size_t)bm * 128 * K + (size_t)arow * K + akseg;
    const __bf16* gB = Bm + (size_t)bn * 128 * K + (size_t)arow * K + akseg;
    __bf16* lA = &sA[0][0] + wave * 512;
    __bf16* lB = &sB[0][0] + wave * 512;

    const int kq   = (lane >> 4) * 8;
    const int mrow = lane & 15;

    for (int k0 = 0; k0 < K; k0 += 32) {
        async_copy16(gA,          lA);
        async_copy16(gA + 64 * K, lA + 2048);
        async_copy16(gB,          lB);
        async_copy16(gB + 64 * K, lB + 2048);
        gA += 32; gB += 32;
        __syncthreads();

        v8bf af[4], bfr[4];
        #pragma unroll
        for (int i = 0; i < 4; ++i) af[i]  = *(v8bf*)&sA[wm + i * 16 + mrow][kq];
        #pragma unroll
        for (int j = 0; j < 4; ++j) bfr[j] = *(v8bf*)&sB[wn + j * 16 + mrow][kq];
        #pragma unroll
        for (int i = 0; i < 4; ++i)
            #pragma unroll
            for (int j = 0; j < 4; ++j)
                acc[i][j] = __builtin_amdgcn_mfma_f32_16x16x32_bf16(af[i], bfr[j], acc[i][j], 0, 0, 0);
        __syncthreads();
    }

    const int ccol  = lane & 15;
    const int crow4 = (lane >> 4) * 4;
    #pragma unroll
    for (int i = 0; i < 4; ++i)
        #pragma unroll
        for (int j = 0; j < 4; ++j) {
            int gm = bm * 128 + wm + i * 16 + crow4;
            int gn = bn * 128 + wn + j * 16 + ccol;
            #pragma unroll
            for (int r = 0; r < 4; ++r)
                Cout[(size_t)(gm + r) * Nn + gn] = acc[i][j][r];
        }
}

// ---------------- fused gate-mix + residual + LayerNorm ----------------
__global__ __launch_bounds__(256) void fuse_ln(const float* __restrict__ tokens,
                                               const float* __restrict__ hrel,
                                               const float* __restrict__ habs_in,
                                               const float* __restrict__ W_abs,
                                               const float* __restrict__ alpha,
                                               const float* __restrict__ gamma,
                                               const float* __restrict__ beta,
                                               float* __restrict__ out) {
    const int row = blockIdx.x;
    const int b   = row >> 9;
    const float al = alpha[b];
    const float a0 = habs_in[(size_t)row * 2];
    const float a1 = habs_in[(size_t)row * 2 + 1];
    const int tid  = threadIdx.x;
    const int lane = tid & 63;
    const int wave = tid >> 6;

    __shared__ float red[4];

    float x[4];
    float s = 0.0f;
    #pragma unroll
    for (int q = 0; q < 4; ++q) {
        int dcol = tid + q * 256;
        float habs = a0 * W_abs[dcol * 2] + a1 * W_abs[dcol * 2 + 1];
        float v = tokens[(size_t)row * DD + dcol]
                + al * hrel[(size_t)row * DD + dcol]
                + (1.0f - al) * habs;
        x[q] = v;
        s += v;
    }
    #pragma unroll
    for (int off = 32; off > 0; off >>= 1) s += __shfl_down(s, off);
    if (lane == 0) red[wave] = s;
    __syncthreads();
    float mu = (red[0] + red[1] + red[2] + red[3]) * (1.0f / DD);

    float vs = 0.0f;
    #pragma unroll
    for (int q = 0; q < 4; ++q) {
        float d = x[q] - mu;
        vs += d * d;
    }
    #pragma unroll
    for (int off = 32; off > 0; off >>= 1) vs += __shfl_down(vs, off);
    __syncthreads();
    if (lane == 0) red[wave] = vs;
    __syncthreads();
    float var = (red[0] + red[1] + red[2] + red[3]) * (1.0f / DD);
    float rstd = rsqrtf(var + EPS);

    #pragma unroll
    for (int q = 0; q < 4; ++q) {
        int dcol = tid + q * 256;
        out[(size_t)row * DD + dcol] = (x[q] - mu) * rstd * gamma[dcol] + beta[dcol];
    }
}

// ---------------- host launch ----------------
extern "C" void kernel_launch(void* const* d_in, const int* in_sizes, int n_in,
                              void* d_out, int out_size, void* d_ws, size_t ws_size,
                              hipStream_t stream) {
    const float* tokens   = (const float*)d_in[0];
    const float* traj     = (const float*)d_in[1];
    const float* habs     = (const float*)d_in[2];
    const float* espeed   = (const float*)d_in[3];
    const float* gconf    = (const float*)d_in[4];
    const float* W_ih     = (const float*)d_in[5];
    const float* W_hh     = (const float*)d_in[6];
    const float* b_ih     = (const float*)d_in[7];
    const float* b_hh     = (const float*)d_in[8];
    const float* W_rel    = (const float*)d_in[9];
    const float* W_abs    = (const float*)d_in[10];
    const float* W_g1     = (const float*)d_in[11];
    const float* b_g1     = (const float*)d_in[12];
    const float* W_g2     = (const float*)d_in[13];
    const float* b_g2     = (const float*)d_in[14];
    const float* gamma    = (const float*)d_in[15];
    const float* beta     = (const float*)d_in[16];
    float* out = (float*)d_out;

    char* ws = (char*)d_ws;
    size_t off = 0;
    __bf16* whh_b  = (__bf16*)(ws + off); off += (size_t)G4 * HID * 2;     // 2 MB
    __bf16* wrel_b = (__bf16*)(ws + off); off += (size_t)DD * HID * 2;     // 1 MB
    float*  wih_i  = (float*)(ws + off);  off += (size_t)G4 * 4 * 4;       // 32 KB
    float*  bsum   = (float*)(ws + off);  off += (size_t)G4 * 4;           // 8 KB
    __bf16* h0     = (__bf16*)(ws + off); off += (size_t)BN * HID * 2;     // 16 MB
    __bf16* h1     = (__bf16*)(ws + off); off += (size_t)BN * HID * 2;     // 16 MB
    float*  c      = (float*)(ws + off);  off += (size_t)BN * HID * 4;     // 32 MB
    float*  hrel   = (float*)(ws + off);  off += (size_t)BN * DD * 4;      // 64 MB
    float*  alpha  = (float*)(ws + off);  off += 256;

    convert_w<<<(G4 * HID + 255) / 256, 256, 0, stream>>>(W_hh, W_rel, W_ih, b_ih, b_hh,
                                                          whh_b, wrel_b, wih_i, bsum);
    alpha_kernel<<<1, 64, 0, stream>>>(espeed, gconf, W_g1, b_g1, W_g2, b_g2, alpha);
    lstm_cell0<<<(BN * HID) / 256, 256, 0, stream>>>(traj, wih_i, bsum, c, h0);

    __bf16* hbuf[2] = {h0, h1};
    for (int t = 1; t < HLEN; ++t) {
        const __bf16* hin = hbuf[(t + 1) & 1];
        __bf16* hout = hbuf[t & 1];
        gemm_lstm<<<dim3(BN / 128, G4 / 128), 256, 0, stream>>>(hin, whh_b, traj, wih_i, bsum,
                                                                c, hout, t);
    }
    // final h after t=14 is in hbuf[14&1] = h0
    gemm_proj<<<dim3(BN / 128, DD / 128), 256, 0, stream>>>(h0, wrel_b, hrel);
    fuse_ln<<<BN, 256, 0, stream>>>(tokens, hrel, habs, W_abs, alpha, gamma, beta, out);
}

// Round 3
// 1130.074 us; speedup vs baseline: 1.4825x; 1.2191x over previous
//
#include <hip/hip_runtime.h>
#include <hip/hip_bf16.h>
#include <math.h>

// ---------------- problem constants ----------------
#define BB 32
#define NN 512
#define BN 16384          // BB*NN
#define DD 1024
#define HID 512
#define G4 2048           // 4*HID
#define HLEN 15
#define IND 4
#define EPS 1e-5f
#define CLD 132           // padded LDS C stride (bf16)

typedef __bf16 v8bf __attribute__((ext_vector_type(8)));
typedef __bf16 v4bf __attribute__((ext_vector_type(4)));
typedef float  v4f  __attribute__((ext_vector_type(4)));

__device__ __forceinline__ void async_copy16(const __bf16* gsrc, __bf16* ldst) {
    __builtin_amdgcn_global_load_lds(
        (const __attribute__((address_space(1))) void*)gsrc,
        (__attribute__((address_space(3))) void*)ldst, 16, 0, 0);
}

// fast transcendentals: v_exp_f32 + v_rcp_f32 (rel err ~1e-6, fine vs 0.11 threshold)
#define LOG2E 1.44269504f
__device__ __forceinline__ float sigmf(float x) {
    return __builtin_amdgcn_rcpf(1.0f + __builtin_amdgcn_exp2f(-LOG2E * x));
}
__device__ __forceinline__ float tanh_fast(float x) {
    return 1.0f - 2.0f * __builtin_amdgcn_rcpf(1.0f + __builtin_amdgcn_exp2f(2.0f * LOG2E * x));
}

// ---------------- weight prep ----------------
// whh_b: gate-interleaved (j' = u*4+gi) bf16 2048x512; wrel_b: bf16 1024x512;
// wih_i: interleaved fp32 2048x4; bsum: b_ih+b_hh interleaved fp32 2048.
__global__ void convert_w(const float* __restrict__ Whh, const float* __restrict__ Wrel,
                          const float* __restrict__ Wih, const float* __restrict__ bih,
                          const float* __restrict__ bhh,
                          __bf16* __restrict__ whh_b, __bf16* __restrict__ wrel_b,
                          float* __restrict__ wih_i, float* __restrict__ bsum) {
    int i = blockIdx.x * 256 + threadIdx.x;
    if (i < G4 * HID) {
        int jp = i >> 9, k = i & 511;
        int uu = jp >> 2, gi = jp & 3;
        whh_b[i] = (__bf16)Whh[(size_t)(gi * HID + uu) * HID + k];
    }
    if (i < DD * HID) wrel_b[i] = (__bf16)Wrel[i];
    if (i < G4) {
        int uu = i >> 2, gi = i & 3;
        int src = gi * HID + uu;
        wih_i[i * 4 + 0] = Wih[src * 4 + 0];
        wih_i[i * 4 + 1] = Wih[src * 4 + 1];
        wih_i[i * 4 + 2] = Wih[src * 4 + 2];
        wih_i[i * 4 + 3] = Wih[src * 4 + 3];
        bsum[i] = bih[src] + bhh[src];
    }
}

// ---------------- per-batch gate alpha ----------------
__global__ void alpha_kernel(const float* __restrict__ es, const float* __restrict__ gc,
                             const float* __restrict__ W_g1, const float* __restrict__ b_g1,
                             const float* __restrict__ W_g2, const float* __restrict__ b_g2,
                             float* __restrict__ alpha) {
    int b = threadIdx.x;
    if (b >= BB) return;
    float c0 = es[b], c1 = gc[b];
    float acc = b_g2[0];
    for (int k = 0; k < 16; ++k) {
        float hk = c0 * W_g1[k * 2] + c1 * W_g1[k * 2 + 1] + b_g1[k];
        hk = fmaxf(hk, 0.0f);
        acc += hk * W_g2[k];
    }
    alpha[b] = 1.0f / (1.0f + expf(-acc));   // once, keep accurate
}

// ---------------- t=0 cell (h0 = c0 = 0 -> gates from input only) ----------------
__global__ __launch_bounds__(256) void lstm_cell0(const float* __restrict__ traj,
                                                  const float* __restrict__ wih_i,
                                                  const float* __restrict__ bsum,
                                                  float* __restrict__ c,
                                                  __bf16* __restrict__ h) {
    int idx = blockIdx.x * 256 + threadIdx.x;   // row*512 + u
    int row = idx >> 9;
    int u   = idx & 511;
    float4 x = *(const float4*)(traj + (size_t)row * (HLEN * IND));   // t = 0, 16B aligned
    float g[4];
    #pragma unroll
    for (int gi = 0; gi < 4; ++gi) {
        int j = u * 4 + gi;
        float4 w = *(const float4*)(wih_i + (size_t)j * 4);
        g[gi] = bsum[j] + w.x * x.x + w.y * x.y + w.z * x.z + w.w * x.w;
    }
    float ig = sigmf(g[0]);
    float gg = tanh_fast(g[2]);
    float og = sigmf(g[3]);
    float cn = ig * gg;                    // f*c0 = 0
    c[idx] = cn;
    h[idx] = (__bf16)(og * tanh_fast(cn));
}

// ---------------- fused GEMM + LSTM cell ----------------
// C(16384 x 2048) = h_in(16384x512) @ whh^T (gate-interleaved), cell update in epilogue.
__global__ __launch_bounds__(256) void gemm_lstm(const __bf16* __restrict__ A,
                                                 const __bf16* __restrict__ Bm,
                                                 const float* __restrict__ traj,
                                                 const float* __restrict__ wih_i,
                                                 const float* __restrict__ bsum,
                                                 float* __restrict__ c,
                                                 __bf16* __restrict__ h_out,
                                                 int t) {
    __shared__ union {
        struct { __bf16 a[128][32]; __bf16 b[128][32]; } s;
        __bf16 cst[128][CLD];
    } u;
    const int K = HID;
    const int tid  = threadIdx.x;
    const int lane = tid & 63;
    const int wave = tid >> 6;
    const int wm = (wave & 1) * 64;
    const int wn = (wave >> 1) * 64;
    const int bm = blockIdx.x;
    const int bn = blockIdx.y;

    v4f acc[4][4] = {};

    const int arow  = tid >> 2;        // 0..63
    const int akseg = (tid & 3) * 8;   // 0,8,16,24

    const __bf16* gA = A  + (size_t)bm * 128 * K + (size_t)arow * K + akseg;
    const __bf16* gB = Bm + (size_t)bn * 128 * K + (size_t)arow * K + akseg;
    __bf16* lA = &u.s.a[0][0] + wave * 512;
    __bf16* lB = &u.s.b[0][0] + wave * 512;

    const int kq   = (lane >> 4) * 8;
    const int mrow = lane & 15;

    for (int k0 = 0; k0 < K; k0 += 32) {
        async_copy16(gA,            lA);
        async_copy16(gA + 64 * K,   lA + 2048);
        async_copy16(gB,            lB);
        async_copy16(gB + 64 * K,   lB + 2048);
        gA += 32; gB += 32;
        __syncthreads();

        v8bf af[4], bfr[4];
        #pragma unroll
        for (int i = 0; i < 4; ++i) af[i]  = *(v8bf*)&u.s.a[wm + i * 16 + mrow][kq];
        #pragma unroll
        for (int j = 0; j < 4; ++j) bfr[j] = *(v8bf*)&u.s.b[wn + j * 16 + mrow][kq];
        #pragma unroll
        for (int i = 0; i < 4; ++i)
            #pragma unroll
            for (int j = 0; j < 4; ++j)
                acc[i][j] = __builtin_amdgcn_mfma_f32_16x16x32_bf16(af[i], bfr[j], acc[i][j], 0, 0, 0);
        __syncthreads();
    }

    // acc -> LDS (bf16, padded) ; C/D layout: col=lane&15, row=(lane>>4)*4+reg
    const int ccol  = lane & 15;
    const int crow4 = (lane >> 4) * 4;
    #pragma unroll
    for (int i = 0; i < 4; ++i)
        #pragma unroll
        for (int j = 0; j < 4; ++j)
            #pragma unroll
            for (int r = 0; r < 4; ++r)
                u.cst[wm + i * 16 + crow4 + r][wn + j * 16 + ccol] = (__bf16)acc[i][j][r];
    __syncthreads();

    // cell update: this block owns rows [bm*128,+128) x units [bn*32,+32)
    const int u_loc  = tid & 31;
    const int rgrp   = tid >> 5;
    const int u_glob = bn * 32 + u_loc;
    float wv[4][4], bs4[4];
    #pragma unroll
    for (int gi = 0; gi < 4; ++gi) {
        float4 wp = *(const float4*)(wih_i + (size_t)(u_glob * 4 + gi) * 4);
        wv[gi][0] = wp.x; wv[gi][1] = wp.y; wv[gi][2] = wp.z; wv[gi][3] = wp.w;
        bs4[gi] = bsum[u_glob * 4 + gi];
    }
    #pragma unroll
    for (int rr = rgrp; rr < 128; rr += 8) {
        int grow = bm * 128 + rr;
        float4 x = *(const float4*)(traj + (size_t)grow * (HLEN * IND) + t * IND);
        v4bf gv = *(v4bf*)&u.cst[rr][u_loc * 4];      // i,f,g,o gates, 8B contiguous
        float g[4];
        #pragma unroll
        for (int gi = 0; gi < 4; ++gi)
            g[gi] = (float)gv[gi] + bs4[gi]
                  + wv[gi][0] * x.x + wv[gi][1] * x.y + wv[gi][2] * x.z + wv[gi][3] * x.w;
        float ig = sigmf(g[0]);
        float fg = sigmf(g[1]);
        float gg = tanh_fast(g[2]);
        float og = sigmf(g[3]);
        size_t ci = (size_t)grow * HID + u_glob;
        float cn = fg * c[ci] + ig * gg;
        c[ci] = cn;
        h_out[ci] = (__bf16)(og * tanh_fast(cn));
    }
}

// ---------------- projection GEMM: hrel(16384x1024) = h(16384x512) @ W_rel^T ----------------
__global__ __launch_bounds__(256) void gemm_proj(const __bf16* __restrict__ A,
                                                 const __bf16* __restrict__ Bm,
                                                 float* __restrict__ Cout) {
    __shared__ __bf16 sA[128][32];
    __shared__ __bf16 sB[128][32];
    const int K = HID, Nn = DD;
    const int tid  = threadIdx.x;
    const int lane = tid & 63;
    const int wave = tid >> 6;
    const int wm = (wave & 1) * 64;
    const int wn = (wave >> 1) * 64;
    const int bm = blockIdx.x;
    const int bn = blockIdx.y;

    v4f acc[4][4] = {};
    const int arow  = tid >> 2;
    const int akseg = (tid & 3) * 8;

    const __bf16* gA = A  + (size_t)bm * 128 * K + (size_t)arow * K + akseg;
    const __bf16* gB = Bm + (size_t)bn * 128 * K + (size_t)arow * K + akseg;
    __bf16* lA = &sA[0][0] + wave * 512;
    __bf16* lB = &sB[0][0] + wave * 512;

    const int kq   = (lane >> 4) * 8;
    const int mrow = lane & 15;

    for (int k0 = 0; k0 < K; k0 += 32) {
        async_copy16(gA,          lA);
        async_copy16(gA + 64 * K, lA + 2048);
        async_copy16(gB,          lB);
        async_copy16(gB + 64 * K, lB + 2048);
        gA += 32; gB += 32;
        __syncthreads();

        v8bf af[4], bfr[4];
        #pragma unroll
        for (int i = 0; i < 4; ++i) af[i]  = *(v8bf*)&sA[wm + i * 16 + mrow][kq];
        #pragma unroll
        for (int j = 0; j < 4; ++j) bfr[j] = *(v8bf*)&sB[wn + j * 16 + mrow][kq];
        #pragma unroll
        for (int i = 0; i < 4; ++i)
            #pragma unroll
            for (int j = 0; j < 4; ++j)
                acc[i][j] = __builtin_amdgcn_mfma_f32_16x16x32_bf16(af[i], bfr[j], acc[i][j], 0, 0, 0);
        __syncthreads();
    }

    const int ccol  = lane & 15;
    const int crow4 = (lane >> 4) * 4;
    #pragma unroll
    for (int i = 0; i < 4; ++i)
        #pragma unroll
        for (int j = 0; j < 4; ++j) {
            int gm = bm * 128 + wm + i * 16 + crow4;
            int gn = bn * 128 + wn + j * 16 + ccol;
            #pragma unroll
            for (int r = 0; r < 4; ++r)
                Cout[(size_t)(gm + r) * Nn + gn] = acc[i][j][r];
        }
}

// ---------------- fused gate-mix + residual + LayerNorm ----------------
__global__ __launch_bounds__(256) void fuse_ln(const float* __restrict__ tokens,
                                               const float* __restrict__ hrel,
                                               const float* __restrict__ habs_in,
                                               const float* __restrict__ W_abs,
                                               const float* __restrict__ alpha,
                                               const float* __restrict__ gamma,
                                               const float* __restrict__ beta,
                                               float* __restrict__ out) {
    const int row = blockIdx.x;
    const int b   = row >> 9;
    const float al = alpha[b];
    const float a0 = habs_in[(size_t)row * 2];
    const float a1 = habs_in[(size_t)row * 2 + 1];
    const int tid  = threadIdx.x;
    const int lane = tid & 63;
    const int wave = tid >> 6;

    __shared__ float red[4];

    float x[4];
    float s = 0.0f;
    #pragma unroll
    for (int q = 0; q < 4; ++q) {
        int dcol = tid + q * 256;
        float habs = a0 * W_abs[dcol * 2] + a1 * W_abs[dcol * 2 + 1];
        float v = tokens[(size_t)row * DD + dcol]
                + al * hrel[(size_t)row * DD + dcol]
                + (1.0f - al) * habs;
        x[q] = v;
        s += v;
    }
    #pragma unroll
    for (int off = 32; off > 0; off >>= 1) s += __shfl_down(s, off);
    if (lane == 0) red[wave] = s;
    __syncthreads();
    float mu = (red[0] + red[1] + red[2] + red[3]) * (1.0f / DD);

    float vs = 0.0f;
    #pragma unroll
    for (int q = 0; q < 4; ++q) {
        float d = x[q] - mu;
        vs += d * d;
    }
    #pragma unroll
    for (int off = 32; off > 0; off >>= 1) vs += __shfl_down(vs, off);
    __syncthreads();
    if (lane == 0) red[wave] = vs;
    __syncthreads();
    float var = (red[0] + red[1] + red[2] + red[3]) * (1.0f / DD);
    float rstd = rsqrtf(var + EPS);

    #pragma unroll
    for (int q = 0; q < 4; ++q) {
        int dcol = tid + q * 256;
        out[(size_t)row * DD + dcol] = (x[q] - mu) * rstd * gamma[dcol] + beta[dcol];
    }
}

// ---------------- host launch ----------------
extern "C" void kernel_launch(void* const* d_in, const int* in_sizes, int n_in,
                              void* d_out, int out_size, void* d_ws, size_t ws_size,
                              hipStream_t stream) {
    const float* tokens   = (const float*)d_in[0];
    const float* traj     = (const float*)d_in[1];
    const float* habs     = (const float*)d_in[2];
    const float* espeed   = (const float*)d_in[3];
    const float* gconf    = (const float*)d_in[4];
    const float* W_ih     = (const float*)d_in[5];
    const float* W_hh     = (const float*)d_in[6];
    const float* b_ih     = (const float*)d_in[7];
    const float* b_hh     = (const float*)d_in[8];
    const float* W_rel    = (const float*)d_in[9];
    const float* W_abs    = (const float*)d_in[10];
    const float* W_g1     = (const float*)d_in[11];
    const float* b_g1     = (const float*)d_in[12];
    const float* W_g2     = (const float*)d_in[13];
    const float* b_g2     = (const float*)d_in[14];
    const float* gamma    = (const float*)d_in[15];
    const float* beta     = (const float*)d_in[16];
    float* out = (float*)d_out;

    char* ws = (char*)d_ws;
    size_t off = 0;
    __bf16* whh_b  = (__bf16*)(ws + off); off += (size_t)G4 * HID * 2;     // 2 MB
    __bf16* wrel_b = (__bf16*)(ws + off); off += (size_t)DD * HID * 2;     // 1 MB
    float*  wih_i  = (float*)(ws + off);  off += (size_t)G4 * 4 * 4;       // 32 KB
    float*  bsum   = (float*)(ws + off);  off += (size_t)G4 * 4;           // 8 KB
    __bf16* h0     = (__bf16*)(ws + off); off += (size_t)BN * HID * 2;     // 16 MB
    __bf16* h1     = (__bf16*)(ws + off); off += (size_t)BN * HID * 2;     // 16 MB
    float*  c      = (float*)(ws + off);  off += (size_t)BN * HID * 4;     // 32 MB
    float*  hrel   = (float*)(ws + off);  off += (size_t)BN * DD * 4;      // 64 MB
    float*  alpha  = (float*)(ws + off);  off += 256;

    convert_w<<<(G4 * HID + 255) / 256, 256, 0, stream>>>(W_hh, W_rel, W_ih, b_ih, b_hh,
                                                          whh_b, wrel_b, wih_i, bsum);
    alpha_kernel<<<1, 64, 0, stream>>>(espeed, gconf, W_g1, b_g1, W_g2, b_g2, alpha);
    lstm_cell0<<<(BN * HID) / 256, 256, 0, stream>>>(traj, wih_i, bsum, c, h0);

    __bf16* hbuf[2] = {h0, h1};
    for (int t = 1; t < HLEN; ++t) {
        const __bf16* hin = hbuf[(t + 1) & 1];
        __bf16* hout = hbuf[t & 1];
        gemm_lstm<<<dim3(BN / 128, G4 / 128), 256, 0, stream>>>(hin, whh_b, traj, wih_i, bsum,
                                                                c, hout, t);
    }
    // final h after t=14 is in hbuf[14&1] = h0
    gemm_proj<<<dim3(BN / 128, DD / 128), 256, 0, stream>>>(h0, wrel_b, hrel);
    fuse_ln<<<BN, 256, 0, stream>>>(tokens, hrel, habs, W_abs, alpha, gamma, beta, out);
}